// Round 3
// baseline (40.238 us; speedup 1.0000x reference)
//
#include <hip/hip_runtime.h>

// Problem constants (from the reference)
#define BB 16
#define SS 4096
#define CC 512
#define NPOS (BB * SS)           // 65536 mask positions
#define OUT_ELEMS (BB * SS * CC) // 33554432 floats for `out`
#define N4 (OUT_ELEMS / 4)       // float4 count

// ---------------- Threefry-2x32, 20 rounds, key = (0, 42) -------------------
// Partitionable counter-mode (jax_threefry_partitionable=True, default since
// JAX 0.4.30): per element i, hash x = (hi32(i), lo32(i)) = (0, i) with
// key (0, 42); 32-bit output = o1 ^ o2.
__device__ __forceinline__ unsigned rotl32(unsigned x, unsigned d) {
    return (x << d) | (x >> (32u - d));
}

__device__ __forceinline__ unsigned threefry_bits(unsigned i) {
    const unsigned k0 = 0u;
    const unsigned k1 = 42u;
    const unsigned k2 = 0u ^ 42u ^ 0x1BD11BDAu;
    unsigned v0 = 0u + k0;   // counts_hi + ks0
    unsigned v1 = i + k1;    // counts_lo + ks1

#define TF_RND(r) { v0 += v1; v1 = rotl32(v1, (r)); v1 ^= v0; }
    TF_RND(13) TF_RND(15) TF_RND(26) TF_RND(6)
    v0 += k1; v1 += k2 + 1u;
    TF_RND(17) TF_RND(29) TF_RND(16) TF_RND(24)
    v0 += k2; v1 += k0 + 2u;
    TF_RND(13) TF_RND(15) TF_RND(26) TF_RND(6)
    v0 += k0; v1 += k1 + 3u;
    TF_RND(17) TF_RND(29) TF_RND(16) TF_RND(24)
    v0 += k1; v1 += k2 + 4u;
    TF_RND(13) TF_RND(15) TF_RND(26) TF_RND(6)
    v0 += k2; v1 += k0 + 5u;
#undef TF_RND

    return v0 ^ v1;          // XOR-fold of the 2x32 PRF output
}

// Bernoulli(0.065) sample at flat position i, exactly as jax.random.bernoulli
__device__ __forceinline__ int sparse_at(int i) {
    unsigned bits = threefry_bits((unsigned)i);
    unsigned fb = (bits >> 9) | 0x3f800000u;
    float u = __uint_as_float(fb) - 1.0f;   // uniform in [0,1), 23 mantissa bits
    return (u < 0.065f) ? 1 : 0;
}

// ---------------- Kernel 1: mask (sparse -> dilate -> last-col quirk) -------
// One block = 256 consecutive positions within one row (256 | 4096).
__global__ __launch_bounds__(256) void mask_kernel(float* __restrict__ maskf) {
    __shared__ int sp[256 + 10];            // halo: 5 before, 4 after, +1 spare
    const int base = blockIdx.x * 256;
    const int rowstart = base & ~(SS - 1);  // row boundary (rows are 4096-aligned)

    for (int k = threadIdx.x; k < 266; k += 256) {
        int p = base - 5 + k;
        int v = 0;
        if (p >= rowstart && p < rowstart + SS) v = sparse_at(p);  // zero pad outside row
        sp[k] = v;
    }
    __syncthreads();

    const int i = base + threadIdx.x;
    const int j = i & (SS - 1);
    int m;
    if (j == SS - 1) {
        m = sp[threadIdx.x + 5];            // last position: sparse only, no dilation
    } else {
        m = 0;
#pragma unroll
        for (int w = 0; w < 10; ++w) m |= sp[threadIdx.x + w];  // window [j-5, j+4]
    }
    maskf[i] = (float)m;                    // second output ({0,1} as f32)
}

// ---------------- Kernel 2: masked scatter of mask_item ---------------------
__global__ __launch_bounds__(256) void apply_kernel(const float4* __restrict__ seq,
                                                    const float4* __restrict__ mi,
                                                    const float* __restrict__ maskf,
                                                    float4* __restrict__ out) {
    const int stride = gridDim.x * blockDim.x;
    for (int i = blockIdx.x * blockDim.x + threadIdx.x; i < N4; i += stride) {
        const int pos = i >> 7;             // 128 float4 per (b, s) position
        float4 v;
        if (maskf[pos] != 0.0f) {
            v = mi[i & 127];                // 2KB, L1-resident
        } else {
            v = seq[i];                     // skipped entirely for masked spans
        }
        out[i] = v;
    }
}

extern "C" void kernel_launch(void* const* d_in, const int* in_sizes, int n_in,
                              void* d_out, int out_size, void* d_ws, size_t ws_size,
                              hipStream_t stream) {
    const float* seq = (const float*)d_in[0];
    const float* mask_item = (const float*)d_in[1];
    float* out = (float*)d_out;
    float* maskf = out + OUT_ELEMS;         // tuple output #2 lives at the tail

    mask_kernel<<<NPOS / 256, 256, 0, stream>>>(maskf);
    apply_kernel<<<2048, 256, 0, stream>>>((const float4*)seq,
                                           (const float4*)mask_item,
                                           maskf,
                                           (float4*)out);
}

// Round 4
// 36.939 us; speedup vs baseline: 1.0893x; 1.0893x over previous
//
#include <hip/hip_runtime.h>

// Problem constants (from the reference)
#define BB 16
#define SS 4096
#define CC 512
#define NPOS (BB * SS)           // 65536 mask positions
#define OUT_ELEMS (BB * SS * CC) // 33554432 floats for `out`

#define POS_PER_BLK 32           // positions per block (divides 4096: no row-crossing)
#define F4_PER_POS (CC / 4)      // 128 float4 per position
#define F4_PER_BLK (POS_PER_BLK * F4_PER_POS)  // 4096 float4 per block

typedef float vfloat4 __attribute__((ext_vector_type(4)));

// ---------------- Threefry-2x32, 20 rounds, key = (0, 42) -------------------
// Partitionable counter-mode (JAX >= 0.4.30 default): per element i, hash
// x = (hi32(i), lo32(i)) = (0, i) with key (0, 42); 32-bit out = v0 ^ v1.
__device__ __forceinline__ unsigned rotl32(unsigned x, unsigned d) {
    return (x << d) | (x >> (32u - d));
}

__device__ __forceinline__ unsigned threefry_bits(unsigned i) {
    const unsigned k0 = 0u;
    const unsigned k1 = 42u;
    const unsigned k2 = 0u ^ 42u ^ 0x1BD11BDAu;
    unsigned v0 = 0u + k0;   // counts_hi + ks0
    unsigned v1 = i + k1;    // counts_lo + ks1

#define TF_RND(r) { v0 += v1; v1 = rotl32(v1, (r)); v1 ^= v0; }
    TF_RND(13) TF_RND(15) TF_RND(26) TF_RND(6)
    v0 += k1; v1 += k2 + 1u;
    TF_RND(17) TF_RND(29) TF_RND(16) TF_RND(24)
    v0 += k2; v1 += k0 + 2u;
    TF_RND(13) TF_RND(15) TF_RND(26) TF_RND(6)
    v0 += k0; v1 += k1 + 3u;
    TF_RND(17) TF_RND(29) TF_RND(16) TF_RND(24)
    v0 += k1; v1 += k2 + 4u;
    TF_RND(13) TF_RND(15) TF_RND(26) TF_RND(6)
    v0 += k2; v1 += k0 + 5u;
#undef TF_RND

    return v0 ^ v1;          // XOR-fold of the 2x32 PRF output
}

__device__ __forceinline__ int sparse_at(int i) {
    unsigned bits = threefry_bits((unsigned)i);
    unsigned fb = (bits >> 9) | 0x3f800000u;
    float u = __uint_as_float(fb) - 1.0f;   // uniform in [0,1), 23 mantissa bits
    return (u < 0.065f) ? 1 : 0;
}

// ---------------- Fused kernel: mask gen + dilate + masked scatter ----------
// One block = 32 consecutive positions of one row. Halo [base-5, base+36)
// clamped to the row. Branch is wave-uniform (64 lanes = half a position).
__global__ __launch_bounds__(256) void fused_kernel(const vfloat4* __restrict__ seq,
                                                    const vfloat4* __restrict__ mi,
                                                    float* __restrict__ maskf,
                                                    vfloat4* __restrict__ out) {
    __shared__ int sp[POS_PER_BLK + 9];     // sparse halo: [base-5, base+36)
    __shared__ int msk[POS_PER_BLK];

    const int base = blockIdx.x * POS_PER_BLK;
    const int rowstart = base & ~(SS - 1);
    const int t = threadIdx.x;

    if (t < POS_PER_BLK + 9) {
        int p = base - 5 + t;
        sp[t] = (p >= rowstart && p < rowstart + SS) ? sparse_at(p) : 0;
    }
    __syncthreads();

    if (t < POS_PER_BLK) {
        const int j = (base + t) & (SS - 1);
        int m;
        if (j == SS - 1) {
            m = sp[t + 5];                  // last position: sparse only
        } else {
            m = 0;
#pragma unroll
            for (int w = 0; w < 10; ++w) m |= sp[t + w];   // window [j-5, j+4]
        }
        msk[t] = m;
        maskf[base + t] = (float)m;         // second output ({0,1} as f32)
    }
    __syncthreads();

    const long long blk_f4 = (long long)blockIdx.x * F4_PER_BLK;
#pragma unroll
    for (int k = t; k < F4_PER_BLK; k += 256) {
        vfloat4 v;
        if (msk[k >> 7]) {
            v = mi[k & (F4_PER_POS - 1)];   // 2KB, L1-resident
        } else {
            v = __builtin_nontemporal_load(&seq[blk_f4 + k]);  // streaming read
        }
        __builtin_nontemporal_store(v, &out[blk_f4 + k]);      // streaming write
    }
}

extern "C" void kernel_launch(void* const* d_in, const int* in_sizes, int n_in,
                              void* d_out, int out_size, void* d_ws, size_t ws_size,
                              hipStream_t stream) {
    const float* seq = (const float*)d_in[0];
    const float* mask_item = (const float*)d_in[1];
    float* out = (float*)d_out;
    float* maskf = out + OUT_ELEMS;         // tuple output #2 lives at the tail

    fused_kernel<<<NPOS / POS_PER_BLK, 256, 0, stream>>>((const vfloat4*)seq,
                                                         (const vfloat4*)mask_item,
                                                         maskf,
                                                         (vfloat4*)out);
}

// Round 5
// 36.087 us; speedup vs baseline: 1.1150x; 1.0236x over previous
//
#include <hip/hip_runtime.h>

// Problem constants (from the reference)
#define BB 16
#define SS 4096
#define CC 512
#define NPOS (BB * SS)           // 65536 mask positions
#define OUT_ELEMS (BB * SS * CC) // 33554432 floats for `out`

#define POS_PER_BLK 32           // positions per block (divides 4096: no row-crossing)
#define F4_PER_POS (CC / 4)      // 128 float4 per position
#define F4_PER_BLK (POS_PER_BLK * F4_PER_POS)   // 4096 float4 per block
#define F4_PER_WAVE 1024         // each of 4 waves owns 8 positions

typedef float vfloat4 __attribute__((ext_vector_type(4)));

// ---------------- Threefry-2x32, 20 rounds, key = (0, 42) -------------------
// Partitionable counter-mode (JAX >= 0.4.30 default): per element i, hash
// x = (hi32(i), lo32(i)) = (0, i) with key (0, 42); 32-bit out = v0 ^ v1.
__device__ __forceinline__ unsigned rotl32(unsigned x, unsigned d) {
    return (x << d) | (x >> (32u - d));
}

__device__ __forceinline__ unsigned threefry_bits(unsigned i) {
    const unsigned k0 = 0u;
    const unsigned k1 = 42u;
    const unsigned k2 = 0u ^ 42u ^ 0x1BD11BDAu;
    unsigned v0 = 0u + k0;   // counts_hi + ks0
    unsigned v1 = i + k1;    // counts_lo + ks1

#define TF_RND(r) { v0 += v1; v1 = rotl32(v1, (r)); v1 ^= v0; }
    TF_RND(13) TF_RND(15) TF_RND(26) TF_RND(6)
    v0 += k1; v1 += k2 + 1u;
    TF_RND(17) TF_RND(29) TF_RND(16) TF_RND(24)
    v0 += k2; v1 += k0 + 2u;
    TF_RND(13) TF_RND(15) TF_RND(26) TF_RND(6)
    v0 += k0; v1 += k1 + 3u;
    TF_RND(17) TF_RND(29) TF_RND(16) TF_RND(24)
    v0 += k1; v1 += k2 + 4u;
    TF_RND(13) TF_RND(15) TF_RND(26) TF_RND(6)
    v0 += k2; v1 += k0 + 5u;
#undef TF_RND

    return v0 ^ v1;          // XOR-fold of the 2x32 PRF output
}

__device__ __forceinline__ int sparse_at(int i) {
    unsigned bits = threefry_bits((unsigned)i);
    unsigned fb = (bits >> 9) | 0x3f800000u;
    float u = __uint_as_float(fb) - 1.0f;   // uniform in [0,1), 23 mantissa bits
    return (u < 0.065f) ? 1 : 0;
}

// ---------------- Fused kernel: ballot mask + masked streaming copy ---------
// Block = 32 consecutive positions of one row. Each wave redundantly builds
// the mask in SGPRs via two ballots (no LDS, no barriers), then streams its
// 8 positions with a scalar (wave-uniform) masked/copy branch.
__global__ __launch_bounds__(256) void fused_kernel(const vfloat4* __restrict__ seq,
                                                    const vfloat4* __restrict__ mi,
                                                    float* __restrict__ maskf,
                                                    vfloat4* __restrict__ out) {
    const int t = threadIdx.x;
    const int lane = t & 63;
    const int w = t >> 6;                   // wave id 0..3
    const int base = blockIdx.x * POS_PER_BLK;
    const int rowstart = base & ~(SS - 1);  // rows are 4096-aligned

    // Ballot 1: bit l = sparse(base-5+l), l = 0..40 (halo), clamped to row
    int sv = 0;
    {
        const int p = base - 5 + lane;
        if (lane <= 40 && p >= rowstart && p < rowstart + SS) sv = sparse_at(p);
    }
    const unsigned long long bal = __ballot(sv);

    // Ballot 2: bit t0 = dilated mask of position base+t0 (t0 = 0..31)
    int m_t = 0;
    if (lane < 32) {
        const int j = (base + lane) & (SS - 1);
        if (j == SS - 1) m_t = (int)((bal >> (lane + 5)) & 1ull);  // sparse only
        else             m_t = ((bal >> lane) & 0x3FFull) != 0ull; // window [j-5, j+4]
    }
    const unsigned M = (unsigned)__ballot(m_t);   // 32 mask bits, SGPR

    if (t < 32) maskf[base + t] = (float)((M >> t) & 1u);  // second output

    // Streaming: wave w owns f4 range [w*1024, (w+1)*1024) of this block
    const long long blk_f4 = (long long)blockIdx.x * F4_PER_BLK;
    const int wbase = w * F4_PER_WAVE;
    const int posbase = __builtin_amdgcn_readfirstlane(w * 8);
#pragma unroll
    for (int it = 0; it < 16; ++it) {
        const int k = wbase + it * 64 + lane;
        const int pos = posbase + (it >> 1);          // scalar + compile-time
        vfloat4 v;
        if ((M >> pos) & 1u) {                        // wave-uniform scalar branch
            v = mi[k & (F4_PER_POS - 1)];             // 2KB, L1-resident
        } else {
            v = __builtin_nontemporal_load(&seq[blk_f4 + k]);
        }
        __builtin_nontemporal_store(v, &out[blk_f4 + k]);
    }
}

extern "C" void kernel_launch(void* const* d_in, const int* in_sizes, int n_in,
                              void* d_out, int out_size, void* d_ws, size_t ws_size,
                              hipStream_t stream) {
    const float* seq = (const float*)d_in[0];
    const float* mask_item = (const float*)d_in[1];
    float* out = (float*)d_out;
    float* maskf = out + OUT_ELEMS;         // tuple output #2 lives at the tail

    fused_kernel<<<NPOS / POS_PER_BLK, 256, 0, stream>>>((const vfloat4*)seq,
                                                         (const vfloat4*)mask_item,
                                                         maskf,
                                                         (vfloat4*)out);
}